// Round 4
// baseline (39847.635 us; speedup 1.0000x reference)
//
#include <hip/hip_runtime.h>
#include <cmath>

#define NB   256
#define NT   64
#define DATA 256
#define DD   264
#define WID  256
#define NSUB 4
#define NTH  512

// ---- dynamic LDS layout (float offsets) ----
#define L_W2LO 0            // [128][256] k-major low half of W2  = 32768
#define L_PS   32768        // [8][256] per-wave partial sums     = 2048
#define L_Y    34816        // 264
#define L_IN   35080        // 264
#define L_K    35344        // 264
#define L_ACC  35608        // 264
#define L_H1   35872        // 256
#define L_H2   36128        // 256
#define L_TMP  36384        // 256
#define L_B0   36640        // 256
#define L_B1   36896        // 256
#define L_B2   37152        // 256
#define L_B3   37408        // 264
#define LDS_FLOATS 37672    // 150,688 bytes -> forces 1 block/CU

// d_ws: wt1[k*256+j] = W1[j][k] (65536 floats), wt2lo[k*256+j] = W2[j][k] k<128 (32768)
__global__ void prep_transpose(const float* __restrict__ W1,
                               const float* __restrict__ W2,
                               float* __restrict__ ws) {
  int tid = blockIdx.x * blockDim.x + threadIdx.x;
  int stride = gridDim.x * blockDim.x;
  for (int i = tid; i < WID * WID; i += stride) {
    int k = i >> 8, j = i & 255;
    ws[i] = W1[j * WID + k];
  }
  for (int i = tid; i < 128 * WID; i += stride) {
    int k = i >> 8, j = i & 255;
    ws[WID * WID + i] = W2[j * WID + k];
  }
}

__device__ __forceinline__ float wave_sum(float v) {
#pragma unroll
  for (int o = 32; o > 0; o >>= 1) v += __shfl_xor(v, o);
  return v;
}

__device__ __forceinline__ void f_eval(
    const float* __restrict__ fin,    // [264] LDS
    float* __restrict__ sm,
    const float4 (&w1c)[32],
    const float* __restrict__ W0,
    const float* __restrict__ W2,
    const float* __restrict__ W3,
    int wave, int lane, int tid) {
  float* s_h1 = sm + L_H1;
  float* s_h2 = sm + L_H2;
  float* s_tmp = sm + L_TMP;
  float* ps = sm + L_PS;
  float* w2lo = sm + L_W2LO;
  float* s_k = sm + L_K;

  // ---- L0: h1 = tanh(W0 @ fin + b0); row-per-wave, K=264, coalesced 1KB row bursts
  {
    const float4* fin4 = (const float4*)fin;
    float4 f0 = fin4[lane];
    float4 ft; ft.x = ft.y = ft.z = ft.w = 0.f;
    if (lane < 2) ft = fin4[64 + lane];
    float keep = 0.f;
#pragma unroll 4
    for (int r = 0; r < 32; ++r) {
      int j = wave + 8 * r;
      const float4* wr = (const float4*)(W0 + (size_t)j * DD);
      float4 wv = wr[lane];
      float s = wv.x * f0.x + wv.y * f0.y + wv.z * f0.z + wv.w * f0.w;
      if (lane < 2) {
        float4 wt = wr[64 + lane];
        s += wt.x * ft.x + wt.y * ft.y + wt.z * ft.z + wt.w * ft.w;
      }
      s = wave_sum(s);
      if (lane == r) keep = s;
    }
    if (lane < 32) {
      int j = wave + 8 * lane;
      s_h1[j] = tanhf(keep + sm[L_B0 + j]);
    }
  }
  __syncthreads();

  // ---- L1: h2 = tanh(W1 @ h1 + b1); k-broadcast from REGISTER cache
  {
    float4 a0, a1;
    a0.x = a0.y = a0.z = a0.w = 0.f; a1 = a0;
#pragma unroll
    for (int i = 0; i < 32; i += 2) {
      float fk0 = s_h1[wave + 8 * i];
      float fk1 = s_h1[wave + 8 * (i + 1)];
      a0.x = fmaf(w1c[i].x, fk0, a0.x);
      a0.y = fmaf(w1c[i].y, fk0, a0.y);
      a0.z = fmaf(w1c[i].z, fk0, a0.z);
      a0.w = fmaf(w1c[i].w, fk0, a0.w);
      a1.x = fmaf(w1c[i + 1].x, fk1, a1.x);
      a1.y = fmaf(w1c[i + 1].y, fk1, a1.y);
      a1.z = fmaf(w1c[i + 1].z, fk1, a1.z);
      a1.w = fmaf(w1c[i + 1].w, fk1, a1.w);
    }
    float4 acc;
    acc.x = a0.x + a1.x; acc.y = a0.y + a1.y;
    acc.z = a0.z + a1.z; acc.w = a0.w + a1.w;
    ((float4*)(ps + wave * WID))[lane] = acc;
  }
  __syncthreads();
  if (tid < WID) {
    float s = sm[L_B1 + tid];
#pragma unroll
    for (int w = 0; w < 8; ++w) s += ps[w * WID + tid];
    s_h2[tid] = tanhf(s);
  }
  __syncthreads();

  // ---- L2a: rows, k=128..255 streamed from W2 (row-major, coalesced float2)
  {
    float2 f2 = ((const float2*)(s_h2 + 128))[lane];
    float keep = 0.f;
#pragma unroll 4
    for (int r = 0; r < 32; ++r) {
      int j = wave + 8 * r;
      const float2* wr = (const float2*)(W2 + (size_t)j * WID + 128);
      float2 wv = wr[lane];
      float s = wv.x * f2.x + wv.y * f2.y;
      s = wave_sum(s);
      if (lane == r) keep = s;
    }
    if (lane < 32) s_tmp[wave + 8 * lane] = keep;
  }
  // ---- L2b: k<128 k-broadcast from LDS cache
  {
    float4 a0; a0.x = a0.y = a0.z = a0.w = 0.f;
#pragma unroll
    for (int i = 0; i < 16; ++i) {
      int k = wave + 8 * i;
      float fk = s_h2[k];
      float4 wv = ((const float4*)w2lo)[k * 64 + lane];
      a0.x = fmaf(wv.x, fk, a0.x);
      a0.y = fmaf(wv.y, fk, a0.y);
      a0.z = fmaf(wv.z, fk, a0.z);
      a0.w = fmaf(wv.w, fk, a0.w);
    }
    ((float4*)(ps + wave * WID))[lane] = a0;
  }
  __syncthreads();
  if (tid < WID) {
    float s = sm[L_B2 + tid] + s_tmp[tid];
#pragma unroll
    for (int w = 0; w < 8; ++w) s += ps[w * WID + tid];
    s_h1[tid] = tanhf(s);
  }
  __syncthreads();

  // ---- L3: f = W3 @ h + b3; row-per-wave, 33 rows/wave, K=256
  {
    float4 f0 = ((const float4*)s_h1)[lane];
    float keep = 0.f;
#pragma unroll 4
    for (int r = 0; r < 33; ++r) {
      int j = wave + 8 * r;
      const float4* wr = (const float4*)(W3 + (size_t)j * WID);
      float4 wv = wr[lane];
      float s = wv.x * f0.x + wv.y * f0.y + wv.z * f0.z + wv.w * f0.w;
      s = wave_sum(s);
      if (lane == r) keep = s;
    }
    if (lane < 33) {
      int j = wave + 8 * lane;
      s_k[j] = keep + sm[L_B3 + j];
    }
  }
  __syncthreads();
}

__global__ __launch_bounds__(NTH, 2) void node_integrate(
    const float* __restrict__ ts, const float* __restrict__ xs,
    const float* __restrict__ a_sample,
    const float* __restrict__ W0, const float* __restrict__ b0,
    const float* __restrict__ b1, const float* __restrict__ W2,
    const float* __restrict__ b2, const float* __restrict__ W3,
    const float* __restrict__ b3, const float* __restrict__ ws,
    float* __restrict__ out) {
  extern __shared__ float sm[];
  const int b = blockIdx.x;
  const int tid = threadIdx.x;
  const int wave = tid >> 6;
  const int lane = tid & 63;

  // one-time fills
  for (int i = tid; i < WID; i += NTH) {
    sm[L_B0 + i] = b0[i];
    sm[L_B1 + i] = b1[i];
    sm[L_B2 + i] = b2[i];
  }
  for (int i = tid; i < DD; i += NTH) sm[L_B3 + i] = b3[i];
  {
    const float4* src = (const float4*)(ws + WID * WID);
    float4* dst = (float4*)(sm + L_W2LO);
    for (int i = tid; i < 128 * WID / 4; i += NTH) dst[i] = src[i];
  }
  float4 w1c[32];
  {
    const float4* wt1 = (const float4*)ws;
#pragma unroll
    for (int i = 0; i < 32; ++i) w1c[i] = wt1[(wave + 8 * i) * 64 + lane];
  }
  // y0 = concat(a * exp(-0.1*t0) * sin(pi*x), zeros(AUG))
  if (tid < DD) {
    float v = 0.f;
    if (tid < DATA) {
      float x = xs[(size_t)b * DATA + tid];
      float scale = a_sample[b] * expf(-0.1f * ts[0]);
      v = scale * sinf(3.14159265358979323846f * x);
    }
    sm[L_Y + tid] = v;
  }
  __syncthreads();

  if (tid < DATA) out[((size_t)b * NT) * DATA + tid] = sm[L_Y + tid];

  float* s_y = sm + L_Y;
  float* s_in = sm + L_IN;
  float* s_k = sm + L_K;
  float* s_acc = sm + L_ACC;

  for (int t = 0; t < NT - 1; ++t) {
    const float dt = ts[t + 1] - ts[t];
    const float h = dt * (1.0f / NSUB);
    for (int sub = 0; sub < NSUB; ++sub) {
      f_eval(s_y, sm, w1c, W0, W2, W3, wave, lane, tid);
      if (tid < DD) {
        float k1 = s_k[tid];
        s_acc[tid] = (2.0f / 9.0f) * k1;
        s_in[tid] = s_y[tid] + 0.5f * h * k1;
      }
      __syncthreads();
      f_eval(s_in, sm, w1c, W0, W2, W3, wave, lane, tid);
      if (tid < DD) {
        float k2 = s_k[tid];
        s_acc[tid] += (1.0f / 3.0f) * k2;
        s_in[tid] = s_y[tid] + 0.75f * h * k2;
      }
      __syncthreads();
      f_eval(s_in, sm, w1c, W0, W2, W3, wave, lane, tid);
      if (tid < DD) {
        float k3 = s_k[tid];
        s_y[tid] += h * (s_acc[tid] + (4.0f / 9.0f) * k3);
      }
      __syncthreads();
    }
    if (tid < DATA) out[((size_t)b * NT + (t + 1)) * DATA + tid] = sm[L_Y + tid];
  }
}

extern "C" void kernel_launch(void* const* d_in, const int* in_sizes, int n_in,
                              void* d_out, int out_size, void* d_ws, size_t ws_size,
                              hipStream_t stream) {
  const float* ts = (const float*)d_in[0];
  const float* xs = (const float*)d_in[1];
  const float* a  = (const float*)d_in[2];
  const float* W0 = (const float*)d_in[3];
  const float* b0 = (const float*)d_in[4];
  const float* W1 = (const float*)d_in[5];
  const float* b1 = (const float*)d_in[6];
  const float* W2 = (const float*)d_in[7];
  const float* b2 = (const float*)d_in[8];
  const float* W3 = (const float*)d_in[9];
  const float* b3 = (const float*)d_in[10];
  float* ws = (float*)d_ws;
  float* out = (float*)d_out;

  const size_t lds_bytes = LDS_FLOATS * sizeof(float);
  hipFuncSetAttribute(reinterpret_cast<const void*>(node_integrate),
                      hipFuncAttributeMaxDynamicSharedMemorySize,
                      (int)lds_bytes);

  hipLaunchKernelGGL(prep_transpose, dim3(64), dim3(256), 0, stream, W1, W2, ws);
  hipLaunchKernelGGL(node_integrate, dim3(NB), dim3(NTH), lds_bytes, stream,
                     ts, xs, a, W0, b0, b1, W2, b2, W3, b3, ws, out);
}